// Round 8
// baseline (578.734 us; speedup 1.0000x reference)
//
#include <hip/hip_runtime.h>
#include <hip/hip_fp16.h>
#include <math.h>

#define BB   16
#define SS   1024
#define PP   1024
#define HH   8
#define MSS  32
#define EE   524288
#define NROW (BB*SS)   /* 16384 */
#define NCOL (BB*PP)   /* 16384 */
#define ESTRIDE 5      /* dwords per edge entry: [0]=other id, [1..4]=8 x fp16 ev */
#define NBPX 2112      /* edge blocks per XCD slot */
#define NB   128       /* hist/pos blocks */
#define CHUNK 4096     /* edges per hist/pos block */

// ============ tiled fp32 GEMM core: C_tile[64 x 128] = A[64 x 128] @ B[128 x 128-slice]
__device__ __forceinline__ void gemm_tile_core(
        const float* __restrict__ Arow, const float* __restrict__ Bsrc,
        int ldb, int c0, float* As /*64*132*/, float* Bs /*32*128*/,
        float4 acc4[8], int t) {
    int tx = t & 31, ty = t >> 5;
#pragma unroll
    for (int li = 0; li < 8; li++) {
        int idx = li * 256 + t;
        int r = idx >> 5, p = idx & 31;
        *(float4*)&As[r * 132 + 4 * p] = *(const float4*)(Arow + r * 128 + 4 * p);
    }
#pragma unroll
    for (int i = 0; i < 8; i++) acc4[i] = make_float4(0.f, 0.f, 0.f, 0.f);

    for (int kc = 0; kc < 4; kc++) {
        __syncthreads();
#pragma unroll
        for (int li = 0; li < 4; li++) {
            int idx = li * 256 + t;
            int kk = idx >> 5, p = idx & 31;
            *(float4*)&Bs[kk * 128 + 4 * p] =
                *(const float4*)(Bsrc + (size_t)(kc * 32 + kk) * ldb + c0 + 4 * p);
        }
        __syncthreads();
#pragma unroll
        for (int kq = 0; kq < 8; kq++) {
            float4 a4[8];
#pragma unroll
            for (int i = 0; i < 8; i++)
                a4[i] = *(const float4*)&As[(ty + 8 * i) * 132 + kc * 32 + kq * 4];
#pragma unroll
            for (int kk = 0; kk < 4; kk++) {
                float4 b4 = *(const float4*)&Bs[(kq * 4 + kk) * 128 + 4 * tx];
#pragma unroll
                for (int i = 0; i < 8; i++) {
                    float av = ((const float*)&a4[i])[kk];
                    acc4[i].x = fmaf(av, b4.x, acc4[i].x);
                    acc4[i].y = fmaf(av, b4.y, acc4[i].y);
                    acc4[i].z = fmaf(av, b4.z, acc4[i].z);
                    acc4[i].w = fmaf(av, b4.w, acc4[i].w);
                }
            }
        }
    }
}

// ---------------- projection (pure GEMM now; histogram moved out) -----------
__global__ __launch_bounds__(256) void proj_kernel(
        const float* __restrict__ x1, const float* __restrict__ x2,
        const float* __restrict__ Wqv1, const float* __restrict__ Wkv2,
        float* __restrict__ qf, float* __restrict__ kf,
        __half* __restrict__ v1h, __half* __restrict__ v2h) {
    __shared__ float As[64 * 132];
    __shared__ float Bs[32 * 128];
    int t = threadIdx.x;
    int bid = blockIdx.x;
    int matrix = bid >> 9;
    int ct = (bid >> 8) & 1;
    int mb = bid & 255;
    const float* A  = matrix ? x2 : x1;
    const float* Bm = matrix ? Wkv2 : Wqv1;

    float4 acc4[8];
    gemm_tile_core(A + (size_t)mb * 64 * 128, Bm, 256, ct * 128, As, Bs, acc4, t);

    int tx = t & 31, ty = t >> 5;
    if (ct == 0) {
        float* Cq = matrix ? kf : qf;
#pragma unroll
        for (int i = 0; i < 8; i++) {
            int row = mb * 64 + ty + 8 * i;
            *(float4*)(Cq + (size_t)row * 128 + 4 * tx) = acc4[i];
        }
    } else {
        __half* Cv = matrix ? v2h : v1h;
#pragma unroll
        for (int i = 0; i < 8; i++) {
            int row = mb * 64 + ty + 8 * i;
            __half2* p = (__half2*)(Cv + (size_t)row * 128 + 4 * tx);
            p[0] = __halves2half2(__float2half(acc4[i].x), __float2half(acc4[i].y));
            p[1] = __halves2half2(__float2half(acc4[i].z), __float2half(acc4[i].w));
        }
    }
}

// ---------------- output GEMMs ----------------------------------------------
__global__ __launch_bounds__(256) void outp_kernel(
        const float* __restrict__ rh, const float* __restrict__ ch,
        const float* __restrict__ Wo1, const float* __restrict__ Wo2,
        float* __restrict__ out) {
    __shared__ float As[64 * 132];
    __shared__ float Bs[32 * 128];
    int t = threadIdx.x;
    int matrix = blockIdx.x >> 8;
    int mb = blockIdx.x & 255;
    const float* A  = matrix ? ch : rh;
    const float* Bm = matrix ? Wo2 : Wo1;
    float* C = out + (size_t)matrix * NROW * 128;

    float4 acc4[8];
    gemm_tile_core(A + (size_t)mb * 64 * 128, Bm, 128, 0, As, Bs, acc4, t);

    int tx = t & 31, ty = t >> 5;
#pragma unroll
    for (int i = 0; i < 8; i++) {
        int row = mb * 64 + ty + 8 * i;
        *(float4*)(C + (size_t)row * 128 + 4 * tx) = acc4[i];
    }
}

// ---------------- atomic-free histogram: per-block LDS, u16-packed ----------
// lh[16384] ints = 32768 u16 bins (row bins 0..16383, col bins 16384..32767).
// Max count per (block,bin) = CHUNK=4096 < 65536, no overflow. Dense dump.
__global__ __launch_bounds__(1024) void hist_kernel(
        const int* __restrict__ b_idx, const int* __restrict__ s_idx,
        const int* __restrict__ p_idx, unsigned int* __restrict__ ph) {
    __shared__ unsigned int lh[16384];
    int t = threadIdx.x;
#pragma unroll
    for (int i = 0; i < 16; i++) lh[t + 1024 * i] = 0;
    __syncthreads();
    int base = blockIdx.x * CHUNK;
#pragma unroll
    for (int k = 0; k < 4; k++) {
        int e = base + k * 1024 + t;
        int b = b_idx[e];
        int rbin = (b << 10) + s_idx[e];
        int cbin = 16384 + (b << 10) + p_idx[e];
        atomicAdd(&lh[rbin >> 1], 1u << (16 * (rbin & 1)));
        atomicAdd(&lh[cbin >> 1], 1u << (16 * (cbin & 1)));
    }
    __syncthreads();
    unsigned int* dst = ph + (size_t)blockIdx.x * 16384;
#pragma unroll
    for (int i = 0; i < 16; i++) dst[t + 1024 * i] = lh[t + 1024 * i];
}

// ---------------- scan: totals -> offs; block-prefixes -> pbase -------------
// blockIdx = side (0 rows, 1 cols). Thread t owns bins 16t..16t+15; each
// thread's 16 bins = 8 packed u32 = two int4 loads per j, coalesced.
__global__ __launch_bounds__(1024) void scan_kernel(
        const unsigned int* __restrict__ ph, int* __restrict__ offs,
        int* __restrict__ pbase) {
    int side = blockIdx.x;
    int t = threadIdx.x;
    int tot[16];
#pragma unroll
    for (int i = 0; i < 16; i++) tot[i] = 0;
    for (int j = 0; j < NB; j++) {
        const unsigned int* src = ph + (size_t)j * 16384 + side * 8192 + 8 * t;
#pragma unroll
        for (int u = 0; u < 8; u++) {
            unsigned int v = src[u];
            tot[2 * u]     += v & 0xffff;
            tot[2 * u + 1] += v >> 16;
        }
    }
    int loc[16];
    int run = 0;
#pragma unroll
    for (int i = 0; i < 16; i++) { loc[i] = run; run += tot[i]; }
    __shared__ int sdata[1024];
    sdata[t] = run;
    __syncthreads();
    for (int st = 1; st < 1024; st <<= 1) {
        int v = (t >= st) ? sdata[t - st] : 0;
        __syncthreads();
        sdata[t] += v;
        __syncthreads();
    }
    int excl = sdata[t] - run;
    int* o = offs + side * (16384 + 1);
    int pre[16];
#pragma unroll
    for (int i = 0; i < 16; i++) { int val = excl + loc[i]; o[16 * t + i] = val; pre[i] = val; }
    if (t == 1023) o[16384] = sdata[1023];
    for (int j = 0; j < NB; j++) {
        const unsigned int* src = ph + (size_t)j * 16384 + side * 8192 + 8 * t;
        int* dst = pbase + (size_t)j * 32768 + side * 16384 + 16 * t;
#pragma unroll
        for (int u = 0; u < 8; u++) {
            unsigned int v = src[u];
            dst[2 * u]     = pre[2 * u];     pre[2 * u]     += v & 0xffff;
            dst[2 * u + 1] = pre[2 * u + 1]; pre[2 * u + 1] += v >> 16;
        }
    }
}

// ---------------- posC: col positions via LDS cursors (no global atomics) ---
__global__ __launch_bounds__(1024) void posc_kernel(
        const int* __restrict__ b_idx, const int* __restrict__ p_idx,
        const int* __restrict__ pbase, int* __restrict__ pc_of_e) {
    __shared__ int cur[16384];
    int t = threadIdx.x;
    const int* src = pbase + (size_t)blockIdx.x * 32768 + 16384;
#pragma unroll
    for (int i = 0; i < 16; i++) cur[t + 1024 * i] = src[t + 1024 * i];
    __syncthreads();
    int base = blockIdx.x * CHUNK;
#pragma unroll
    for (int k = 0; k < 4; k++) {
        int e = base + k * 1024 + t;
        int cbin = (b_idx[e] << 10) + p_idx[e];
        pc_of_e[e] = atomicAdd(&cur[cbin], 1);
    }
}

// ---------------- posR: row positions; write full record at ebuf[pr] --------
__global__ __launch_bounds__(1024) void posr_kernel(
        const int* __restrict__ b_idx, const int* __restrict__ s_idx,
        const int* __restrict__ p_idx, const float* __restrict__ w,
        const int* __restrict__ pbase, const int* __restrict__ pc_of_e,
        int4* __restrict__ ebuf) {
    __shared__ int cur[16384];
    int t = threadIdx.x;
    const int* src = pbase + (size_t)blockIdx.x * 32768;
#pragma unroll
    for (int i = 0; i < 16; i++) cur[t + 1024 * i] = src[t + 1024 * i];
    __syncthreads();
    int base = blockIdx.x * CHUNK;
#pragma unroll
    for (int k = 0; k < 4; k++) {
        int e = base + k * 1024 + t;
        int b = b_idx[e];
        int row = (b << 10) + s_idx[e];
        int col = (b << 10) + p_idx[e];
        int pr = atomicAdd(&cur[row], 1);
        ebuf[pr] = make_int4(row, col, __float_as_int(w[e]), pc_of_e[e]);
    }
}

// ---------------- fused edge pass (row-sorted, XCD-pinned, atomic-free) -----
// ebuf is row-sorted (=batch-sorted). entr[i] sequential; entc[pc] batch-local.
__global__ __launch_bounds__(256) void edge_kernel(
        const float* __restrict__ qf, const float* __restrict__ kf,
        const int4* __restrict__ ebuf, const int* __restrict__ offs_row,
        const float* __restrict__ msW1, const float* __restrict__ msb1,
        const float* __restrict__ msW2, const float* __restrict__ msb2,
        float* __restrict__ entr, float* __restrict__ entc) {
    __shared__ float4 sPk[8 * 33];
    __shared__ float sB2[8];
    int t = threadIdx.x;
    {
        int h = t >> 5, m = t & 31;
        sPk[h * 33 + m] = make_float4(msW1[h * 64 + m], msW1[h * 64 + 32 + m],
                                      msb1[h * 32 + m], msW2[h * 32 + m]);
    }
    if (t < 8) sB2[t] = msb2[t];
    __syncthreads();

    int x = blockIdx.x & 7;
    int r0 = blockIdx.x >> 3;
    int a0 = offs_row[x << 10],       a1 = offs_row[(x + 1) << 10];
    int b0 = offs_row[(x + 8) << 10], b1 = offs_row[(x + 9) << 10];
    int nA = a1 - a0;
    int n = nA + (b1 - b0);

    int l = t & 7;
    int sub = t >> 3;
    int hh = 2 * (l & 3) + (l >> 2);
    const float4* wp = &sPk[hh * 33];
    float bias2 = sB2[hh];

    for (int jb = r0 * 32; jb < n; jb += NBPX * 32) {
        int j = jb + sub;
        if (j < n) {
            int pos = (j < nA) ? (a0 + j) : (b0 + (j - nA));
            int4 rec = ebuf[pos];
            int row = rec.x, col = rec.y;
            float we = __int_as_float(rec.z);
            int pc = rec.w;

            const float4* qp4 = (const float4*)(qf + (size_t)row * 128);
            const float4* kp4 = (const float4*)(kf + (size_t)col * 128);
            float p0, p1, p2, p3;
            {
                float4 a = qp4[l],      k4 = kp4[l];
                p0 = fmaf(a.x, k4.x, fmaf(a.y, k4.y, fmaf(a.z, k4.z, a.w * k4.w)));
            }
            {
                float4 a = qp4[8 + l],  k4 = kp4[8 + l];
                p1 = fmaf(a.x, k4.x, fmaf(a.y, k4.y, fmaf(a.z, k4.z, a.w * k4.w)));
            }
            {
                float4 a = qp4[16 + l], k4 = kp4[16 + l];
                p2 = fmaf(a.x, k4.x, fmaf(a.y, k4.y, fmaf(a.z, k4.z, a.w * k4.w)));
            }
            {
                float4 a = qp4[24 + l], k4 = kp4[24 + l];
                p3 = fmaf(a.x, k4.x, fmaf(a.y, k4.y, fmaf(a.z, k4.z, a.w * k4.w)));
            }
            p0 += __shfl_xor(p0, 1); p0 += __shfl_xor(p0, 2);
            p1 += __shfl_xor(p1, 1); p1 += __shfl_xor(p1, 2);
            p2 += __shfl_xor(p2, 1); p2 += __shfl_xor(p2, 2);
            p3 += __shfl_xor(p3, 1); p3 += __shfl_xor(p3, 2);

            int js = l & 3;
            float dot = js == 0 ? p0 : (js == 1 ? p1 : (js == 2 ? p2 : p3));
            float logit = dot * 0.25f;

            float outv = bias2;
#pragma unroll 4
            for (int m = 0; m < MSS; m++) {
                float4 c = wp[m];
                float hid = fmaf(logit, c.x, fmaf(we, c.y, c.z));
                hid = fmaxf(hid, 0.f);
                outv = fmaf(hid, c.w, outv);
            }
            float ev = expf(10.0f * tanhf(outv));
            __half evh = __float2half(ev);

            float* er = entr + (size_t)pos * ESTRIDE;
            float* ec = entc + (size_t)pc * ESTRIDE;
            ((__half*)er)[2 + hh] = evh;
            ((__half*)ec)[2 + hh] = evh;
            if (l == 0) {
                er[0] = __int_as_float(col);
                ec[0] = __int_as_float(row);
            }
        }
    }
}

// ---------------- dual group-softmax combine (XCD-pinned) -------------------
__global__ __launch_bounds__(128) void combine_kernel(
        const float* __restrict__ entr, const float* __restrict__ entc,
        const int* __restrict__ offs_row, const int* __restrict__ offs_col,
        const __half* __restrict__ v1h, const __half* __restrict__ v2h,
        float* __restrict__ row_heads, float* __restrict__ col_heads) {
    int x = blockIdx.x & 7;
    int r = blockIdx.x >> 3;
    int which = r >> 10;
    int sidx = r & 1023;
    int b = x + ((which & 1) << 3);
    int gl = (b << 10) + sidx;

    int t = threadIdx.x;
    int h = t >> 4;
    const float* ent; const __half* vals; const int* offs; float* outp;
    if (which < 2) { ent = entr; vals = v2h; offs = offs_row; outp = row_heads; }
    else           { ent = entc; vals = v1h; offs = offs_col; outp = col_heads; }
    int s = offs[gl], e_ = offs[gl + 1];
    float acc = 0.f, den = 0.f;
#pragma unroll 4
    for (int i = s; i < e_; i++) {
        const float* en = ent + (size_t)i * ESTRIDE;
        int other = __float_as_int(en[0]);
        float ev = __half2float(((const __half*)en)[2 + h]);
        float v = __half2float(vals[(size_t)other * 128 + t]);
        acc = fmaf(ev, v, acc);
        den += ev;
    }
    outp[(size_t)gl * 128 + t] = acc / (den + 1e-9f);
}

extern "C" void kernel_launch(void* const* d_in, const int* in_sizes, int n_in,
                              void* d_out, int out_size, void* d_ws, size_t ws_size,
                              hipStream_t stream) {
    const float* x1   = (const float*)d_in[0];
    const float* x2   = (const float*)d_in[1];
    const int* b_idx  = (const int*)d_in[2];
    const int* s_idx  = (const int*)d_in[3];
    const int* p_idx  = (const int*)d_in[4];
    const float* w    = (const float*)d_in[5];
    const float* Wqv1 = (const float*)d_in[6];
    const float* Wkv2 = (const float*)d_in[7];
    const float* Wo1  = (const float*)d_in[8];
    const float* Wo2  = (const float*)d_in[9];
    const float* msW1 = (const float*)d_in[10];
    const float* msb1 = (const float*)d_in[11];
    const float* msW2 = (const float*)d_in[12];
    const float* msb2 = (const float*)d_in[13];
    float* out = (float*)d_out;

    // Workspace (~72 MiB) with aliased scratch (lifetimes disjoint):
    float* qf = (float*)d_ws;                         // 8.39 MB
    float* kf = qf + (size_t)NROW * 128;              // 8.39 MB
    __half* v1h = (__half*)(kf + (size_t)NCOL * 128); // 4.19 MB
    __half* v2h = v1h + (size_t)NROW * 128;           // 4.19 MB
    float* entr = (float*)(v2h + (size_t)NCOL * 128); // 10.49 MB
    float* entc = entr + (size_t)EE * ESTRIDE;        // 10.49 MB
    float* row_heads = entc + (size_t)EE * ESTRIDE;   // 8.39 MB
    float* col_heads = row_heads + (size_t)NROW * 128;// 8.39 MB
    int4* ebuf = (int4*)(col_heads + (size_t)NCOL * 128); // 8.39 MB
    int* offs = (int*)(ebuf + EE);                    // 2*(16384+1) ints
    // aliases: ph -> entc region (dead until edge); pbase -> heads (dead until
    // combine); pc_of_e -> entr region (dead until edge).
    unsigned int* ph = (unsigned int*)entc;           // NB*16384 u32 = 8.39 MB
    int* pbase = (int*)row_heads;                     // NB*32768 int = 16.78 MB
    int* pc_of_e = (int*)entr;                        // EE int = 2.1 MB

    hist_kernel<<<NB, 1024, 0, stream>>>(b_idx, s_idx, p_idx, ph);
    scan_kernel<<<2, 1024, 0, stream>>>(ph, offs, pbase);
    posc_kernel<<<NB, 1024, 0, stream>>>(b_idx, p_idx, pbase, pc_of_e);
    posr_kernel<<<NB, 1024, 0, stream>>>(b_idx, s_idx, p_idx, w, pbase, pc_of_e, ebuf);

    proj_kernel<<<1024, 256, 0, stream>>>(x1, x2, Wqv1, Wkv2, qf, kf, v1h, v2h);

    edge_kernel<<<8 * NBPX, 256, 0, stream>>>(
        qf, kf, ebuf, offs, msW1, msb1, msW2, msb2, entr, entc);

    combine_kernel<<<2 * NROW, 128, 0, stream>>>(
        entr, entc, offs, offs + (NROW + 1), v1h, v2h, row_heads, col_heads);

    outp_kernel<<<512, 256, 0, stream>>>(row_heads, col_heads, Wo1, Wo2, out);
}

// Round 9
// 264.201 us; speedup vs baseline: 2.1905x; 2.1905x over previous
//
#include <hip/hip_runtime.h>
#include <hip/hip_fp16.h>
#include <math.h>

#define BB   16
#define SS   1024
#define PP   1024
#define HH   8
#define MSS  32
#define EE   524288
#define NROW (BB*SS)   /* 16384 */
#define NCOL (BB*PP)   /* 16384 */
#define ESTRIDE 5      /* dwords per edge entry: [0]=other id, [1..4]=8 x fp16 ev */
#define NBPX 2112      /* edge blocks per XCD slot */
#define NB   128       /* hist/pos blocks */
#define CHUNK 4096     /* edges per hist/pos block */

// ============ tiled fp32 GEMM core: C_tile[64 x 128] = A[64 x 128] @ B[128 x 128-slice]
__device__ __forceinline__ void gemm_tile_core(
        const float* __restrict__ Arow, const float* __restrict__ Bsrc,
        int ldb, int c0, float* As /*64*132*/, float* Bs /*32*128*/,
        float4 acc4[8], int t) {
    int tx = t & 31, ty = t >> 5;
#pragma unroll
    for (int li = 0; li < 8; li++) {
        int idx = li * 256 + t;
        int r = idx >> 5, p = idx & 31;
        *(float4*)&As[r * 132 + 4 * p] = *(const float4*)(Arow + r * 128 + 4 * p);
    }
#pragma unroll
    for (int i = 0; i < 8; i++) acc4[i] = make_float4(0.f, 0.f, 0.f, 0.f);

    for (int kc = 0; kc < 4; kc++) {
        __syncthreads();
#pragma unroll
        for (int li = 0; li < 4; li++) {
            int idx = li * 256 + t;
            int kk = idx >> 5, p = idx & 31;
            *(float4*)&Bs[kk * 128 + 4 * p] =
                *(const float4*)(Bsrc + (size_t)(kc * 32 + kk) * ldb + c0 + 4 * p);
        }
        __syncthreads();
#pragma unroll
        for (int kq = 0; kq < 8; kq++) {
            float4 a4[8];
#pragma unroll
            for (int i = 0; i < 8; i++)
                a4[i] = *(const float4*)&As[(ty + 8 * i) * 132 + kc * 32 + kq * 4];
#pragma unroll
            for (int kk = 0; kk < 4; kk++) {
                float4 b4 = *(const float4*)&Bs[(kq * 4 + kk) * 128 + 4 * tx];
#pragma unroll
                for (int i = 0; i < 8; i++) {
                    float av = ((const float*)&a4[i])[kk];
                    acc4[i].x = fmaf(av, b4.x, acc4[i].x);
                    acc4[i].y = fmaf(av, b4.y, acc4[i].y);
                    acc4[i].z = fmaf(av, b4.z, acc4[i].z);
                    acc4[i].w = fmaf(av, b4.w, acc4[i].w);
                }
            }
        }
    }
}

// ---------------- projection (pure GEMM) ------------------------------------
__global__ __launch_bounds__(256) void proj_kernel(
        const float* __restrict__ x1, const float* __restrict__ x2,
        const float* __restrict__ Wqv1, const float* __restrict__ Wkv2,
        float* __restrict__ qf, float* __restrict__ kf,
        __half* __restrict__ v1h, __half* __restrict__ v2h) {
    __shared__ float As[64 * 132];
    __shared__ float Bs[32 * 128];
    int t = threadIdx.x;
    int bid = blockIdx.x;
    int matrix = bid >> 9;
    int ct = (bid >> 8) & 1;
    int mb = bid & 255;
    const float* A  = matrix ? x2 : x1;
    const float* Bm = matrix ? Wkv2 : Wqv1;

    float4 acc4[8];
    gemm_tile_core(A + (size_t)mb * 64 * 128, Bm, 256, ct * 128, As, Bs, acc4, t);

    int tx = t & 31, ty = t >> 5;
    if (ct == 0) {
        float* Cq = matrix ? kf : qf;
#pragma unroll
        for (int i = 0; i < 8; i++) {
            int row = mb * 64 + ty + 8 * i;
            *(float4*)(Cq + (size_t)row * 128 + 4 * tx) = acc4[i];
        }
    } else {
        __half* Cv = matrix ? v2h : v1h;
#pragma unroll
        for (int i = 0; i < 8; i++) {
            int row = mb * 64 + ty + 8 * i;
            __half2* p = (__half2*)(Cv + (size_t)row * 128 + 4 * tx);
            p[0] = __halves2half2(__float2half(acc4[i].x), __float2half(acc4[i].y));
            p[1] = __halves2half2(__float2half(acc4[i].z), __float2half(acc4[i].w));
        }
    }
}

// ---------------- output GEMMs ----------------------------------------------
__global__ __launch_bounds__(256) void outp_kernel(
        const float* __restrict__ rh, const float* __restrict__ ch,
        const float* __restrict__ Wo1, const float* __restrict__ Wo2,
        float* __restrict__ out) {
    __shared__ float As[64 * 132];
    __shared__ float Bs[32 * 128];
    int t = threadIdx.x;
    int matrix = blockIdx.x >> 8;
    int mb = blockIdx.x & 255;
    const float* A  = matrix ? ch : rh;
    const float* Bm = matrix ? Wo2 : Wo1;
    float* C = out + (size_t)matrix * NROW * 128;

    float4 acc4[8];
    gemm_tile_core(A + (size_t)mb * 64 * 128, Bm, 128, 0, As, Bs, acc4, t);

    int tx = t & 31, ty = t >> 5;
#pragma unroll
    for (int i = 0; i < 8; i++) {
        int row = mb * 64 + ty + 8 * i;
        *(float4*)(C + (size_t)row * 128 + 4 * tx) = acc4[i];
    }
}

// ---------------- atomic-free histogram: per-block LDS, u16-packed ----------
__global__ __launch_bounds__(1024) void hist_kernel(
        const int* __restrict__ b_idx, const int* __restrict__ s_idx,
        const int* __restrict__ p_idx, unsigned int* __restrict__ ph) {
    __shared__ unsigned int lh[16384];
    int t = threadIdx.x;
#pragma unroll
    for (int i = 0; i < 16; i++) lh[t + 1024 * i] = 0;
    __syncthreads();
    int base = blockIdx.x * CHUNK;
#pragma unroll
    for (int k = 0; k < 4; k++) {
        int e = base + k * 1024 + t;
        int b = b_idx[e];
        int rbin = (b << 10) + s_idx[e];
        int cbin = 16384 + (b << 10) + p_idx[e];
        atomicAdd(&lh[rbin >> 1], 1u << (16 * (rbin & 1)));
        atomicAdd(&lh[cbin >> 1], 1u << (16 * (cbin & 1)));
    }
    __syncthreads();
    unsigned int* dst = ph + (size_t)blockIdx.x * 16384;
#pragma unroll
    for (int i = 0; i < 16; i++) dst[t + 1024 * i] = lh[t + 1024 * i];
}

// ---- scan1: per-bin serial prefix over the 128 block-partials --------------
// 256 blocks x 128 threads; thread = one bin. Writes WITHIN-BIN prefixes
// (offs added later in posC/posR) + bin totals. unroll 8 batches the
// independent ph loads so the loop-carried accumulate doesn't serialize on
// memory latency. (Round-8 scan: grid=2 -> 2 CUs -> 73 GB/s, 333 us.)
__global__ __launch_bounds__(128) void scan1_kernel(
        const unsigned int* __restrict__ ph, int* __restrict__ pbase,
        int* __restrict__ tot) {
    int bin = blockIdx.x * 128 + threadIdx.x;   // 0..32767
    int word = bin >> 1;
    int sh = 16 * (bin & 1);
    int run = 0;
#pragma unroll 8
    for (int j = 0; j < NB; j++) {
        unsigned int v = ph[(size_t)j * 16384 + word];
        pbase[(size_t)j * 32768 + bin] = run;
        run += (v >> sh) & 0xffff;
    }
    tot[bin] = run;
}

// ---- scan2: exclusive scan of 16384 bin totals per side -> offs ------------
__global__ __launch_bounds__(1024) void scan2_kernel(
        const int* __restrict__ tot, int* __restrict__ offs) {
    __shared__ int sdata[1024];
    int side = blockIdx.x;
    int t = threadIdx.x;
    const int* c = tot + side * 16384;
    int* o = offs + side * (16384 + 1);
    int base = t * 16;
    int loc[16];
    int run = 0;
#pragma unroll
    for (int i = 0; i < 16; i++) { loc[i] = run; run += c[base + i]; }
    sdata[t] = run;
    __syncthreads();
    for (int st = 1; st < 1024; st <<= 1) {
        int v = (t >= st) ? sdata[t - st] : 0;
        __syncthreads();
        sdata[t] += v;
        __syncthreads();
    }
    int excl = sdata[t] - run;
#pragma unroll
    for (int i = 0; i < 16; i++) o[base + i] = excl + loc[i];
    if (t == 1023) o[16384] = sdata[1023];
}

// ---------------- posC: col positions via LDS cursors -----------------------
// cursor seed = offs_col[bin] + within-bin block prefix.
__global__ __launch_bounds__(1024) void posc_kernel(
        const int* __restrict__ b_idx, const int* __restrict__ p_idx,
        const int* __restrict__ pbase, const int* __restrict__ offs,
        int* __restrict__ pc_of_e) {
    __shared__ int cur[16384];
    int t = threadIdx.x;
    const int* src = pbase + (size_t)blockIdx.x * 32768 + 16384;
    const int* oc = offs + (16384 + 1);
#pragma unroll
    for (int i = 0; i < 16; i++) {
        int idx = t + 1024 * i;
        cur[idx] = oc[idx] + src[idx];
    }
    __syncthreads();
    int base = blockIdx.x * CHUNK;
#pragma unroll
    for (int k = 0; k < 4; k++) {
        int e = base + k * 1024 + t;
        int cbin = (b_idx[e] << 10) + p_idx[e];
        pc_of_e[e] = atomicAdd(&cur[cbin], 1);
    }
}

// ---------------- posR: row positions; write full record at ebuf[pr] --------
__global__ __launch_bounds__(1024) void posr_kernel(
        const int* __restrict__ b_idx, const int* __restrict__ s_idx,
        const int* __restrict__ p_idx, const float* __restrict__ w,
        const int* __restrict__ pbase, const int* __restrict__ offs,
        const int* __restrict__ pc_of_e, int4* __restrict__ ebuf) {
    __shared__ int cur[16384];
    int t = threadIdx.x;
    const int* src = pbase + (size_t)blockIdx.x * 32768;
#pragma unroll
    for (int i = 0; i < 16; i++) {
        int idx = t + 1024 * i;
        cur[idx] = offs[idx] + src[idx];
    }
    __syncthreads();
    int base = blockIdx.x * CHUNK;
#pragma unroll
    for (int k = 0; k < 4; k++) {
        int e = base + k * 1024 + t;
        int b = b_idx[e];
        int row = (b << 10) + s_idx[e];
        int col = (b << 10) + p_idx[e];
        int pr = atomicAdd(&cur[row], 1);
        ebuf[pr] = make_int4(row, col, __float_as_int(w[e]), pc_of_e[e]);
    }
}

// ---------------- fused edge pass (row-sorted, XCD-pinned, atomic-free) -----
__global__ __launch_bounds__(256) void edge_kernel(
        const float* __restrict__ qf, const float* __restrict__ kf,
        const int4* __restrict__ ebuf, const int* __restrict__ offs_row,
        const float* __restrict__ msW1, const float* __restrict__ msb1,
        const float* __restrict__ msW2, const float* __restrict__ msb2,
        float* __restrict__ entr, float* __restrict__ entc) {
    __shared__ float4 sPk[8 * 33];
    __shared__ float sB2[8];
    int t = threadIdx.x;
    {
        int h = t >> 5, m = t & 31;
        sPk[h * 33 + m] = make_float4(msW1[h * 64 + m], msW1[h * 64 + 32 + m],
                                      msb1[h * 32 + m], msW2[h * 32 + m]);
    }
    if (t < 8) sB2[t] = msb2[t];
    __syncthreads();

    int x = blockIdx.x & 7;
    int r0 = blockIdx.x >> 3;
    int a0 = offs_row[x << 10],       a1 = offs_row[(x + 1) << 10];
    int b0 = offs_row[(x + 8) << 10], b1 = offs_row[(x + 9) << 10];
    int nA = a1 - a0;
    int n = nA + (b1 - b0);

    int l = t & 7;
    int sub = t >> 3;
    int hh = 2 * (l & 3) + (l >> 2);
    const float4* wp = &sPk[hh * 33];
    float bias2 = sB2[hh];

    for (int jb = r0 * 32; jb < n; jb += NBPX * 32) {
        int j = jb + sub;
        if (j < n) {
            int pos = (j < nA) ? (a0 + j) : (b0 + (j - nA));
            int4 rec = ebuf[pos];
            int row = rec.x, col = rec.y;
            float we = __int_as_float(rec.z);
            int pc = rec.w;

            const float4* qp4 = (const float4*)(qf + (size_t)row * 128);
            const float4* kp4 = (const float4*)(kf + (size_t)col * 128);
            float p0, p1, p2, p3;
            {
                float4 a = qp4[l],      k4 = kp4[l];
                p0 = fmaf(a.x, k4.x, fmaf(a.y, k4.y, fmaf(a.z, k4.z, a.w * k4.w)));
            }
            {
                float4 a = qp4[8 + l],  k4 = kp4[8 + l];
                p1 = fmaf(a.x, k4.x, fmaf(a.y, k4.y, fmaf(a.z, k4.z, a.w * k4.w)));
            }
            {
                float4 a = qp4[16 + l], k4 = kp4[16 + l];
                p2 = fmaf(a.x, k4.x, fmaf(a.y, k4.y, fmaf(a.z, k4.z, a.w * k4.w)));
            }
            {
                float4 a = qp4[24 + l], k4 = kp4[24 + l];
                p3 = fmaf(a.x, k4.x, fmaf(a.y, k4.y, fmaf(a.z, k4.z, a.w * k4.w)));
            }
            p0 += __shfl_xor(p0, 1); p0 += __shfl_xor(p0, 2);
            p1 += __shfl_xor(p1, 1); p1 += __shfl_xor(p1, 2);
            p2 += __shfl_xor(p2, 1); p2 += __shfl_xor(p2, 2);
            p3 += __shfl_xor(p3, 1); p3 += __shfl_xor(p3, 2);

            int js = l & 3;
            float dot = js == 0 ? p0 : (js == 1 ? p1 : (js == 2 ? p2 : p3));
            float logit = dot * 0.25f;

            float outv = bias2;
#pragma unroll 4
            for (int m = 0; m < MSS; m++) {
                float4 c = wp[m];
                float hid = fmaf(logit, c.x, fmaf(we, c.y, c.z));
                hid = fmaxf(hid, 0.f);
                outv = fmaf(hid, c.w, outv);
            }
            float ev = expf(10.0f * tanhf(outv));
            __half evh = __float2half(ev);

            float* er = entr + (size_t)pos * ESTRIDE;
            float* ec = entc + (size_t)pc * ESTRIDE;
            ((__half*)er)[2 + hh] = evh;
            ((__half*)ec)[2 + hh] = evh;
            if (l == 0) {
                er[0] = __int_as_float(col);
                ec[0] = __int_as_float(row);
            }
        }
    }
}

// ---------------- dual group-softmax combine (XCD-pinned) -------------------
__global__ __launch_bounds__(128) void combine_kernel(
        const float* __restrict__ entr, const float* __restrict__ entc,
        const int* __restrict__ offs_row, const int* __restrict__ offs_col,
        const __half* __restrict__ v1h, const __half* __restrict__ v2h,
        float* __restrict__ row_heads, float* __restrict__ col_heads) {
    int x = blockIdx.x & 7;
    int r = blockIdx.x >> 3;
    int which = r >> 10;
    int sidx = r & 1023;
    int b = x + ((which & 1) << 3);
    int gl = (b << 10) + sidx;

    int t = threadIdx.x;
    int h = t >> 4;
    const float* ent; const __half* vals; const int* offs; float* outp;
    if (which < 2) { ent = entr; vals = v2h; offs = offs_row; outp = row_heads; }
    else           { ent = entc; vals = v1h; offs = offs_col; outp = col_heads; }
    int s = offs[gl], e_ = offs[gl + 1];
    float acc = 0.f, den = 0.f;
#pragma unroll 4
    for (int i = s; i < e_; i++) {
        const float* en = ent + (size_t)i * ESTRIDE;
        int other = __float_as_int(en[0]);
        float ev = __half2float(((const __half*)en)[2 + h]);
        float v = __half2float(vals[(size_t)other * 128 + t]);
        acc = fmaf(ev, v, acc);
        den += ev;
    }
    outp[(size_t)gl * 128 + t] = acc / (den + 1e-9f);
}

extern "C" void kernel_launch(void* const* d_in, const int* in_sizes, int n_in,
                              void* d_out, int out_size, void* d_ws, size_t ws_size,
                              hipStream_t stream) {
    const float* x1   = (const float*)d_in[0];
    const float* x2   = (const float*)d_in[1];
    const int* b_idx  = (const int*)d_in[2];
    const int* s_idx  = (const int*)d_in[3];
    const int* p_idx  = (const int*)d_in[4];
    const float* w    = (const float*)d_in[5];
    const float* Wqv1 = (const float*)d_in[6];
    const float* Wkv2 = (const float*)d_in[7];
    const float* Wo1  = (const float*)d_in[8];
    const float* Wo2  = (const float*)d_in[9];
    const float* msW1 = (const float*)d_in[10];
    const float* msb1 = (const float*)d_in[11];
    const float* msW2 = (const float*)d_in[12];
    const float* msb2 = (const float*)d_in[13];
    float* out = (float*)d_out;

    // Workspace (~72 MiB) with aliased scratch (lifetimes disjoint):
    float* qf = (float*)d_ws;                         // 8.39 MB
    float* kf = qf + (size_t)NROW * 128;              // 8.39 MB
    __half* v1h = (__half*)(kf + (size_t)NCOL * 128); // 4.19 MB
    __half* v2h = v1h + (size_t)NROW * 128;           // 4.19 MB
    float* entr = (float*)(v2h + (size_t)NCOL * 128); // 10.49 MB
    float* entc = entr + (size_t)EE * ESTRIDE;        // 10.49 MB
    float* row_heads = entc + (size_t)EE * ESTRIDE;   // 8.39 MB
    float* col_heads = row_heads + (size_t)NROW * 128;// 8.39 MB
    int4* ebuf = (int4*)(col_heads + (size_t)NCOL * 128); // 8.39 MB
    int* offs = (int*)(ebuf + EE);                    // 2*(16384+1) ints
    int* tot  = offs + 2 * (16384 + 1);               // 32768 ints
    // aliases: ph -> entc (dead until edge); pbase -> heads (dead until
    // combine); pc_of_e -> entr (dead until edge).
    unsigned int* ph = (unsigned int*)entc;           // NB*16384 u32 = 8.39 MB
    int* pbase = (int*)row_heads;                     // NB*32768 int = 16.78 MB
    int* pc_of_e = (int*)entr;                        // EE int = 2.1 MB

    hist_kernel<<<NB, 1024, 0, stream>>>(b_idx, s_idx, p_idx, ph);
    scan1_kernel<<<256, 128, 0, stream>>>(ph, pbase, tot);
    scan2_kernel<<<2, 1024, 0, stream>>>(tot, offs);
    posc_kernel<<<NB, 1024, 0, stream>>>(b_idx, p_idx, pbase, offs, pc_of_e);
    posr_kernel<<<NB, 1024, 0, stream>>>(b_idx, s_idx, p_idx, w, pbase, offs,
                                         pc_of_e, ebuf);

    proj_kernel<<<1024, 256, 0, stream>>>(x1, x2, Wqv1, Wkv2, qf, kf, v1h, v2h);

    edge_kernel<<<8 * NBPX, 256, 0, stream>>>(
        qf, kf, ebuf, offs, msW1, msb1, msW2, msb2, entr, entc);

    combine_kernel<<<2 * NROW, 128, 0, stream>>>(
        entr, entc, offs, offs + (16384 + 1), v1h, v2h, row_heads, col_heads);

    outp_kernel<<<512, 256, 0, stream>>>(row_heads, col_heads, Wo1, Wo2, out);
}

// Round 10
// 244.622 us; speedup vs baseline: 2.3658x; 1.0800x over previous
//
#include <hip/hip_runtime.h>
#include <hip/hip_fp16.h>
#include <math.h>

#define BB   16
#define SS   1024
#define PP   1024
#define HH   8
#define MSS  32
#define EE   524288
#define NROW (BB*SS)   /* 16384 */
#define NCOL (BB*PP)   /* 16384 */
#define ESTRIDE 5      /* dwords per edge entry: [0]=other id, [1..4]=8 x fp16 ev */
#define NBPX 2112      /* edge blocks per XCD slot */
#define NB   128       /* hist/pos blocks */
#define CHUNK 4096     /* edges per hist/pos block */
#define GCAP 96        /* staged entries per group in combine (fallback past this) */

// ============ tiled fp32 GEMM core: C_tile[64 x 128] = A[64 x 128] @ B[128 x 128-slice]
__device__ __forceinline__ void gemm_tile_core(
        const float* __restrict__ Arow, const float* __restrict__ Bsrc,
        int ldb, int c0, float* As /*64*132*/, float* Bs /*32*128*/,
        float4 acc4[8], int t) {
    int tx = t & 31, ty = t >> 5;
#pragma unroll
    for (int li = 0; li < 8; li++) {
        int idx = li * 256 + t;
        int r = idx >> 5, p = idx & 31;
        *(float4*)&As[r * 132 + 4 * p] = *(const float4*)(Arow + r * 128 + 4 * p);
    }
#pragma unroll
    for (int i = 0; i < 8; i++) acc4[i] = make_float4(0.f, 0.f, 0.f, 0.f);

    for (int kc = 0; kc < 4; kc++) {
        __syncthreads();
#pragma unroll
        for (int li = 0; li < 4; li++) {
            int idx = li * 256 + t;
            int kk = idx >> 5, p = idx & 31;
            *(float4*)&Bs[kk * 128 + 4 * p] =
                *(const float4*)(Bsrc + (size_t)(kc * 32 + kk) * ldb + c0 + 4 * p);
        }
        __syncthreads();
#pragma unroll
        for (int kq = 0; kq < 8; kq++) {
            float4 a4[8];
#pragma unroll
            for (int i = 0; i < 8; i++)
                a4[i] = *(const float4*)&As[(ty + 8 * i) * 132 + kc * 32 + kq * 4];
#pragma unroll
            for (int kk = 0; kk < 4; kk++) {
                float4 b4 = *(const float4*)&Bs[(kq * 4 + kk) * 128 + 4 * tx];
#pragma unroll
                for (int i = 0; i < 8; i++) {
                    float av = ((const float*)&a4[i])[kk];
                    acc4[i].x = fmaf(av, b4.x, acc4[i].x);
                    acc4[i].y = fmaf(av, b4.y, acc4[i].y);
                    acc4[i].z = fmaf(av, b4.z, acc4[i].z);
                    acc4[i].w = fmaf(av, b4.w, acc4[i].w);
                }
            }
        }
    }
}

// ---------------- projection (pure GEMM) ------------------------------------
__global__ __launch_bounds__(256) void proj_kernel(
        const float* __restrict__ x1, const float* __restrict__ x2,
        const float* __restrict__ Wqv1, const float* __restrict__ Wkv2,
        float* __restrict__ qf, float* __restrict__ kf,
        __half* __restrict__ v1h, __half* __restrict__ v2h) {
    __shared__ float As[64 * 132];
    __shared__ float Bs[32 * 128];
    int t = threadIdx.x;
    int bid = blockIdx.x;
    int matrix = bid >> 9;
    int ct = (bid >> 8) & 1;
    int mb = bid & 255;
    const float* A  = matrix ? x2 : x1;
    const float* Bm = matrix ? Wkv2 : Wqv1;

    float4 acc4[8];
    gemm_tile_core(A + (size_t)mb * 64 * 128, Bm, 256, ct * 128, As, Bs, acc4, t);

    int tx = t & 31, ty = t >> 5;
    if (ct == 0) {
        float* Cq = matrix ? kf : qf;
#pragma unroll
        for (int i = 0; i < 8; i++) {
            int row = mb * 64 + ty + 8 * i;
            *(float4*)(Cq + (size_t)row * 128 + 4 * tx) = acc4[i];
        }
    } else {
        __half* Cv = matrix ? v2h : v1h;
#pragma unroll
        for (int i = 0; i < 8; i++) {
            int row = mb * 64 + ty + 8 * i;
            __half2* p = (__half2*)(Cv + (size_t)row * 128 + 4 * tx);
            p[0] = __halves2half2(__float2half(acc4[i].x), __float2half(acc4[i].y));
            p[1] = __halves2half2(__float2half(acc4[i].z), __float2half(acc4[i].w));
        }
    }
}

// ---------------- output GEMMs ----------------------------------------------
__global__ __launch_bounds__(256) void outp_kernel(
        const float* __restrict__ rh, const float* __restrict__ ch,
        const float* __restrict__ Wo1, const float* __restrict__ Wo2,
        float* __restrict__ out) {
    __shared__ float As[64 * 132];
    __shared__ float Bs[32 * 128];
    int t = threadIdx.x;
    int matrix = blockIdx.x >> 8;
    int mb = blockIdx.x & 255;
    const float* A  = matrix ? ch : rh;
    const float* Bm = matrix ? Wo2 : Wo1;
    float* C = out + (size_t)matrix * NROW * 128;

    float4 acc4[8];
    gemm_tile_core(A + (size_t)mb * 64 * 128, Bm, 128, 0, As, Bs, acc4, t);

    int tx = t & 31, ty = t >> 5;
#pragma unroll
    for (int i = 0; i < 8; i++) {
        int row = mb * 64 + ty + 8 * i;
        *(float4*)(C + (size_t)row * 128 + 4 * tx) = acc4[i];
    }
}

// ---------------- atomic-free histogram: per-block LDS, u16-packed ----------
__global__ __launch_bounds__(1024) void hist_kernel(
        const int* __restrict__ b_idx, const int* __restrict__ s_idx,
        const int* __restrict__ p_idx, unsigned int* __restrict__ ph) {
    __shared__ unsigned int lh[16384];
    int t = threadIdx.x;
#pragma unroll
    for (int i = 0; i < 16; i++) lh[t + 1024 * i] = 0;
    __syncthreads();
    int base = blockIdx.x * CHUNK;
#pragma unroll
    for (int k = 0; k < 4; k++) {
        int e = base + k * 1024 + t;
        int b = b_idx[e];
        int rbin = (b << 10) + s_idx[e];
        int cbin = 16384 + (b << 10) + p_idx[e];
        atomicAdd(&lh[rbin >> 1], 1u << (16 * (rbin & 1)));
        atomicAdd(&lh[cbin >> 1], 1u << (16 * (cbin & 1)));
    }
    __syncthreads();
    unsigned int* dst = ph + (size_t)blockIdx.x * 16384;
#pragma unroll
    for (int i = 0; i < 16; i++) dst[t + 1024 * i] = lh[t + 1024 * i];
}

// ---- scan1: per-bin serial prefix over the 128 block-partials --------------
__global__ __launch_bounds__(128) void scan1_kernel(
        const unsigned int* __restrict__ ph, int* __restrict__ pbase,
        int* __restrict__ tot) {
    int bin = blockIdx.x * 128 + threadIdx.x;   // 0..32767
    int word = bin >> 1;
    int sh = 16 * (bin & 1);
    int run = 0;
#pragma unroll 8
    for (int j = 0; j < NB; j++) {
        unsigned int v = ph[(size_t)j * 16384 + word];
        pbase[(size_t)j * 32768 + bin] = run;
        run += (v >> sh) & 0xffff;
    }
    tot[bin] = run;
}

// ---- scan2: exclusive scan of 16384 bin totals per side -> offs ------------
__global__ __launch_bounds__(1024) void scan2_kernel(
        const int* __restrict__ tot, int* __restrict__ offs) {
    __shared__ int sdata[1024];
    int side = blockIdx.x;
    int t = threadIdx.x;
    const int* c = tot + side * 16384;
    int* o = offs + side * (16384 + 1);
    int base = t * 16;
    int loc[16];
    int run = 0;
#pragma unroll
    for (int i = 0; i < 16; i++) { loc[i] = run; run += c[base + i]; }
    sdata[t] = run;
    __syncthreads();
    for (int st = 1; st < 1024; st <<= 1) {
        int v = (t >= st) ? sdata[t - st] : 0;
        __syncthreads();
        sdata[t] += v;
        __syncthreads();
    }
    int excl = sdata[t] - run;
#pragma unroll
    for (int i = 0; i < 16; i++) o[base + i] = excl + loc[i];
    if (t == 1023) o[16384] = sdata[1023];
}

// ---- pos: merged col+row positioning (posC+posR of round 9) ----------------
// Phase 1: LDS col cursors -> pc into REGISTERS (block only ever needs its own
// chunk's pc). Phase 2: reuse the same 64KB LDS for row cursors -> pr, write
// full record ebuf[pr]={row,col,w,pc}. Saves the pc_of_e global round-trip,
// one dispatch, and a redundant b/p index pass.
__global__ __launch_bounds__(1024) void pos_kernel(
        const int* __restrict__ b_idx, const int* __restrict__ s_idx,
        const int* __restrict__ p_idx, const float* __restrict__ w,
        const int* __restrict__ pbase, const int* __restrict__ offs,
        int4* __restrict__ ebuf) {
    __shared__ int cur[16384];
    int t = threadIdx.x;
    // phase 1: col cursors
    {
        const int* src = pbase + (size_t)blockIdx.x * 32768 + 16384;
        const int* oc = offs + (16384 + 1);
#pragma unroll
        for (int i = 0; i < 16; i++) {
            int idx = t + 1024 * i;
            cur[idx] = oc[idx] + src[idx];
        }
    }
    __syncthreads();
    int base = blockIdx.x * CHUNK;
    int rowr[4], colr[4], pcr[4];
    float wr[4];
#pragma unroll
    for (int k = 0; k < 4; k++) {
        int e = base + k * 1024 + t;
        int b = b_idx[e];
        rowr[k] = (b << 10) + s_idx[e];
        colr[k] = (b << 10) + p_idx[e];
        wr[k] = w[e];
        pcr[k] = atomicAdd(&cur[colr[k]], 1);
    }
    __syncthreads();
    // phase 2: row cursors
    {
        const int* src = pbase + (size_t)blockIdx.x * 32768;
#pragma unroll
        for (int i = 0; i < 16; i++) {
            int idx = t + 1024 * i;
            cur[idx] = offs[idx] + src[idx];
        }
    }
    __syncthreads();
#pragma unroll
    for (int k = 0; k < 4; k++) {
        int pr = atomicAdd(&cur[rowr[k]], 1);
        ebuf[pr] = make_int4(rowr[k], colr[k], __float_as_int(wr[k]), pcr[k]);
    }
}

// ---------------- fused edge pass (row-sorted, XCD-pinned, atomic-free) -----
__global__ __launch_bounds__(256) void edge_kernel(
        const float* __restrict__ qf, const float* __restrict__ kf,
        const int4* __restrict__ ebuf, const int* __restrict__ offs_row,
        const float* __restrict__ msW1, const float* __restrict__ msb1,
        const float* __restrict__ msW2, const float* __restrict__ msb2,
        float* __restrict__ entr, float* __restrict__ entc) {
    __shared__ float4 sPk[8 * 33];
    __shared__ float sB2[8];
    int t = threadIdx.x;
    {
        int h = t >> 5, m = t & 31;
        sPk[h * 33 + m] = make_float4(msW1[h * 64 + m], msW1[h * 64 + 32 + m],
                                      msb1[h * 32 + m], msW2[h * 32 + m]);
    }
    if (t < 8) sB2[t] = msb2[t];
    __syncthreads();

    int x = blockIdx.x & 7;
    int r0 = blockIdx.x >> 3;
    int a0 = offs_row[x << 10],       a1 = offs_row[(x + 1) << 10];
    int b0 = offs_row[(x + 8) << 10], b1 = offs_row[(x + 9) << 10];
    int nA = a1 - a0;
    int n = nA + (b1 - b0);

    int l = t & 7;
    int sub = t >> 3;
    int hh = 2 * (l & 3) + (l >> 2);
    const float4* wp = &sPk[hh * 33];
    float bias2 = sB2[hh];

    for (int jb = r0 * 32; jb < n; jb += NBPX * 32) {
        int j = jb + sub;
        if (j < n) {
            int pos = (j < nA) ? (a0 + j) : (b0 + (j - nA));
            int4 rec = ebuf[pos];
            int row = rec.x, col = rec.y;
            float we = __int_as_float(rec.z);
            int pc = rec.w;

            const float4* qp4 = (const float4*)(qf + (size_t)row * 128);
            const float4* kp4 = (const float4*)(kf + (size_t)col * 128);
            float p0, p1, p2, p3;
            {
                float4 a = qp4[l],      k4 = kp4[l];
                p0 = fmaf(a.x, k4.x, fmaf(a.y, k4.y, fmaf(a.z, k4.z, a.w * k4.w)));
            }
            {
                float4 a = qp4[8 + l],  k4 = kp4[8 + l];
                p1 = fmaf(a.x, k4.x, fmaf(a.y, k4.y, fmaf(a.z, k4.z, a.w * k4.w)));
            }
            {
                float4 a = qp4[16 + l], k4 = kp4[16 + l];
                p2 = fmaf(a.x, k4.x, fmaf(a.y, k4.y, fmaf(a.z, k4.z, a.w * k4.w)));
            }
            {
                float4 a = qp4[24 + l], k4 = kp4[24 + l];
                p3 = fmaf(a.x, k4.x, fmaf(a.y, k4.y, fmaf(a.z, k4.z, a.w * k4.w)));
            }
            p0 += __shfl_xor(p0, 1); p0 += __shfl_xor(p0, 2);
            p1 += __shfl_xor(p1, 1); p1 += __shfl_xor(p1, 2);
            p2 += __shfl_xor(p2, 1); p2 += __shfl_xor(p2, 2);
            p3 += __shfl_xor(p3, 1); p3 += __shfl_xor(p3, 2);

            int js = l & 3;
            float dot = js == 0 ? p0 : (js == 1 ? p1 : (js == 2 ? p2 : p3));
            float logit = dot * 0.25f;

            float outv = bias2;
#pragma unroll 4
            for (int m = 0; m < MSS; m++) {
                float4 c = wp[m];
                float hid = fmaf(logit, c.x, fmaf(we, c.y, c.z));
                hid = fmaxf(hid, 0.f);
                outv = fmaf(hid, c.w, outv);
            }
            float ev = expf(10.0f * tanhf(outv));
            __half evh = __float2half(ev);

            float* er = entr + (size_t)pos * ESTRIDE;
            float* ec = entc + (size_t)pc * ESTRIDE;
            ((__half*)er)[2 + hh] = evh;
            ((__half*)ec)[2 + hh] = evh;
            if (l == 0) {
                er[0] = __int_as_float(col);
                ec[0] = __int_as_float(row);
            }
        }
    }
}

// ---------------- dual group-softmax combine (XCD-pinned, LDS-staged) -------
// Entries staged cooperatively into LDS (one latency round, coalesced), then
// the main loop reads other/ev from LDS and issues 8 independent v-row loads
// in flight (round-9 version chained entry-load -> v-load serially: 55us at
// 8% HBM / 32% VALU = latency-bound).
__global__ __launch_bounds__(128) void combine_kernel(
        const float* __restrict__ entr, const float* __restrict__ entc,
        const int* __restrict__ offs_row, const int* __restrict__ offs_col,
        const __half* __restrict__ v1h, const __half* __restrict__ v2h,
        float* __restrict__ row_heads, float* __restrict__ col_heads) {
    __shared__ float sE[GCAP * ESTRIDE];
    int x = blockIdx.x & 7;
    int r = blockIdx.x >> 3;
    int which = r >> 10;
    int sidx = r & 1023;
    int b = x + ((which & 1) << 3);
    int gl = (b << 10) + sidx;

    int t = threadIdx.x;
    int h = t >> 4;
    const float* ent; const __half* vals; const int* offs; float* outp;
    if (which < 2) { ent = entr; vals = v2h; offs = offs_row; outp = row_heads; }
    else           { ent = entc; vals = v1h; offs = offs_col; outp = col_heads; }
    int s = offs[gl], e_ = offs[gl + 1];
    int cnt = e_ - s;
    int cap = cnt < GCAP ? cnt : GCAP;

    const float* gsrc = ent + (size_t)s * ESTRIDE;
    for (int i = t; i < cap * ESTRIDE; i += 128) sE[i] = gsrc[i];
    __syncthreads();

    float acc = 0.f, den = 0.f;
#pragma unroll 8
    for (int i = 0; i < cap; i++) {
        const float* en = &sE[i * ESTRIDE];
        int other = __float_as_int(en[0]);
        float ev = __half2float(((const __half*)en)[2 + h]);
        float v = __half2float(vals[(size_t)other * 128 + t]);
        acc = fmaf(ev, v, acc);
        den += ev;
    }
    for (int i = cap; i < cnt; i++) {   // pathological-group fallback
        const float* en = gsrc + (size_t)i * ESTRIDE;
        int other = __float_as_int(en[0]);
        float ev = __half2float(((const __half*)en)[2 + h]);
        float v = __half2float(vals[(size_t)other * 128 + t]);
        acc = fmaf(ev, v, acc);
        den += ev;
    }
    outp[(size_t)gl * 128 + t] = acc / (den + 1e-9f);
}

extern "C" void kernel_launch(void* const* d_in, const int* in_sizes, int n_in,
                              void* d_out, int out_size, void* d_ws, size_t ws_size,
                              hipStream_t stream) {
    const float* x1   = (const float*)d_in[0];
    const float* x2   = (const float*)d_in[1];
    const int* b_idx  = (const int*)d_in[2];
    const int* s_idx  = (const int*)d_in[3];
    const int* p_idx  = (const int*)d_in[4];
    const float* w    = (const float*)d_in[5];
    const float* Wqv1 = (const float*)d_in[6];
    const float* Wkv2 = (const float*)d_in[7];
    const float* Wo1  = (const float*)d_in[8];
    const float* Wo2  = (const float*)d_in[9];
    const float* msW1 = (const float*)d_in[10];
    const float* msb1 = (const float*)d_in[11];
    const float* msW2 = (const float*)d_in[12];
    const float* msb2 = (const float*)d_in[13];
    float* out = (float*)d_out;

    // Workspace (~72 MiB) with aliased scratch (lifetimes disjoint):
    float* qf = (float*)d_ws;                         // 8.39 MB
    float* kf = qf + (size_t)NROW * 128;              // 8.39 MB
    __half* v1h = (__half*)(kf + (size_t)NCOL * 128); // 4.19 MB
    __half* v2h = v1h + (size_t)NROW * 128;           // 4.19 MB
    float* entr = (float*)(v2h + (size_t)NCOL * 128); // 10.49 MB
    float* entc = entr + (size_t)EE * ESTRIDE;        // 10.49 MB
    float* row_heads = entc + (size_t)EE * ESTRIDE;   // 8.39 MB
    float* col_heads = row_heads + (size_t)NROW * 128;// 8.39 MB
    int4* ebuf = (int4*)(col_heads + (size_t)NCOL * 128); // 8.39 MB
    int* offs = (int*)(ebuf + EE);                    // 2*(16384+1) ints
    int* tot  = offs + 2 * (16384 + 1);               // 32768 ints
    // aliases: ph -> entc (dead until edge); pbase -> heads (dead until combine).
    unsigned int* ph = (unsigned int*)entc;           // NB*16384 u32 = 8.39 MB
    int* pbase = (int*)row_heads;                     // NB*32768 int = 16.78 MB

    hist_kernel<<<NB, 1024, 0, stream>>>(b_idx, s_idx, p_idx, ph);
    scan1_kernel<<<256, 128, 0, stream>>>(ph, pbase, tot);
    scan2_kernel<<<2, 1024, 0, stream>>>(tot, offs);
    pos_kernel<<<NB, 1024, 0, stream>>>(b_idx, s_idx, p_idx, w, pbase, offs, ebuf);

    proj_kernel<<<1024, 256, 0, stream>>>(x1, x2, Wqv1, Wkv2, qf, kf, v1h, v2h);

    edge_kernel<<<8 * NBPX, 256, 0, stream>>>(
        qf, kf, ebuf, offs, msW1, msb1, msW2, msb2, entr, entc);

    combine_kernel<<<2 * NROW, 128, 0, stream>>>(
        entr, entc, offs, offs + (16384 + 1), v1h, v2h, row_heads, col_heads);

    outp_kernel<<<512, 256, 0, stream>>>(row_heads, col_heads, Wo1, Wo2, out);
}